// Round 5
// baseline (359.616 us; speedup 1.0000x reference)
//
#include <hip/hip_runtime.h>
#include <cstdint>
#include <cstddef>

#define DM 1024
#define NH 16
#define DKH 64
#define DFF 4096
#define NB 2
#define SQL 2048
#define MROWS (NB * SQL) /* 4096 */
#define QKVN 3072

typedef __attribute__((ext_vector_type(8))) __bf16 bf16x8;
typedef __attribute__((ext_vector_type(8))) short short8;
typedef __attribute__((ext_vector_type(4))) float f32x4;

__device__ __forceinline__ unsigned short f2bf(float f) {
    unsigned u = __float_as_uint(f);
    u += 0x7fffu + ((u >> 16) & 1u);
    return (unsigned short)(u >> 16);
}
__device__ __forceinline__ bf16x8 ldfrag(const unsigned short* p) {
    return __builtin_bit_cast(bf16x8, *(const short8*)p);
}
__device__ __forceinline__ void gl_lds16(const void* g, void* lds) {
    __builtin_amdgcn_global_load_lds(
        (const __attribute__((address_space(1))) unsigned int*)g,
        (__attribute__((address_space(3))) unsigned int*)lds, 16, 0, 0);
}
#define MFMA16(a, b, c) __builtin_amdgcn_mfma_f32_16x16x32_bf16(a, b, c, 0, 0, 0)

// Q-side scale: 1/sqrt(64) * log2(e), so softmax runs in exp2 domain (raw v_exp_f32).
#define QSCALE 0.18033688011112042f

// ---------------- merged prep: weight transposes + x cast + logw + bqkv ----------------
__global__ __launch_bounds__(256) void prep_all(const float* __restrict__ Wq,
                                                const float* __restrict__ Wk,
                                                const float* __restrict__ Wv,
                                                const float* __restrict__ Wo,
                                                const float* __restrict__ W1,
                                                const float* __restrict__ W2,
                                                const float* __restrict__ x,
                                                const float* __restrict__ wts,
                                                const float* __restrict__ bq,
                                                const float* __restrict__ bk,
                                                const float* __restrict__ bv,
                                                unsigned short* __restrict__ wqkv_t,
                                                unsigned short* __restrict__ Wo_t,
                                                unsigned short* __restrict__ W1_t,
                                                unsigned short* __restrict__ W2_t,
                                                unsigned short* __restrict__ x_bf,
                                                float* __restrict__ logw,
                                                float* __restrict__ bqkv) {
    const int t = blockIdx.x, tid = threadIdx.x;
    if (t >= 12288) {
        if (t < 16384) {
            int i = ((t - 12288) * 256 + tid) * 4;
            float4 v = *(const float4*)&x[i];
            ushort4 o;
            o.x = f2bf(v.x); o.y = f2bf(v.y); o.z = f2bf(v.z); o.w = f2bf(v.w);
            *(ushort4*)&x_bf[i] = o;
        } else if (t < 16400) {
            int i = (t - 16384) * 256 + tid;
            logw[i] = log2f(wts[i] + 1e-20f);  // log2 domain for exp2 softmax
        } else {
            int i = (t - 16400) * 256 + tid;
            if (i < QKVN)
                bqkv[i] = i < 1024 ? bq[i] * QSCALE : (i < 2048 ? bk[i - 1024] : bv[i - 2048]);
        }
        return;
    }
    __shared__ float tile[32][33];
    const float* in;
    unsigned short* out;
    int K = DM, N = DM, n0, k0;
    float scale = 1.f;
    if (t < 1024)      { in = Wq; out = wqkv_t;                      scale = QSCALE;
                         n0 = (t & 31) * 32;          k0 = (t >> 5) * 32; }
    else if (t < 2048) { in = Wk; out = wqkv_t + (size_t)1024 * DM;
                         n0 = ((t - 1024) & 31) * 32; k0 = ((t - 1024) >> 5) * 32; }
    else if (t < 3072) { in = Wv; out = wqkv_t + (size_t)2048 * DM;
                         n0 = ((t - 2048) & 31) * 32; k0 = ((t - 2048) >> 5) * 32; }
    else if (t < 4096) { in = Wo; out = Wo_t;
                         n0 = ((t - 3072) & 31) * 32; k0 = ((t - 3072) >> 5) * 32; }
    else if (t < 8192) { in = W1; out = W1_t; N = DFF;
                         n0 = ((t - 4096) & 127) * 32; k0 = ((t - 4096) >> 7) * 32; }
    else               { in = W2; out = W2_t; K = DFF;
                         n0 = ((t - 8192) & 31) * 32;  k0 = ((t - 8192) >> 5) * 32; }
    const int tx = threadIdx.x & 31, ty = threadIdx.x >> 5;
#pragma unroll
    for (int i = 0; i < 32; i += 8)
        tile[ty + i][tx] = in[(size_t)(k0 + ty + i) * N + n0 + tx];
    __syncthreads();
#pragma unroll
    for (int i = 0; i < 32; i += 8)
        out[(size_t)(n0 + ty + i) * K + k0 + tx] = f2bf(tile[tx][ty + i] * scale);
}

// ---------------- bf16 GEMM: C[M,N] = A[M,K] @ Wt[N,K]^T + bias ----------------
// 128 x BN tile, BK=64, global_load_lds 16B staging, XOR-swizzled 16B blocks.
// XCD swizzle: xcd = flat%8 owns gridDim.x/8 consecutive n-blocks (B L2-resident).
// OMODE: 0 = fp32 partials (out + z*M*N), 1 = bf16 row-major, 2 = bf16 row-major for
//        col<2048 and V-transposed (vt[bh][d][s]) for col>=2048 (QKV fused epilogue).
template <int BN, bool RELU, int OMODE, int KSPL>
__global__ __launch_bounds__(256) void gemm_kernel(const unsigned short* __restrict__ A,
                                                   const unsigned short* __restrict__ Wt,
                                                   const float* __restrict__ bias,
                                                   void* __restrict__ outp,
                                                   unsigned short* __restrict__ vtp,
                                                   int M, int N, int K) {
    constexpr int NT = BN / 32;
    __shared__ unsigned short As[128 * 64];
    __shared__ unsigned short Bs[BN * 64];
    const int tid = threadIdx.x;
    const int wave = tid >> 6, lane = tid & 63;
    const int col16 = lane & 15, quad = lane >> 4;
    const int lrow = lane >> 3, sblk = (lane & 7) ^ (lrow & 7);
    // XCD-aware block remap (nper = gridDim.x/8; bijective when gridDim.x % 8 == 0)
    const int f = blockIdx.y * gridDim.x + blockIdx.x;
    const int nper = gridDim.x >> 3;
    const int bx = (f & 7) * nper + (f >> 3) % nper;
    const int by = (f >> 3) / nper;
    const int m0 = by * 128, n0 = bx * BN;
    const int wm = (wave >> 1) * 64, wn = (wave & 1) * (BN / 2);
    const int kbeg = (KSPL > 1) ? blockIdx.z * (K / KSPL) : 0;
    const int kend = kbeg + K / KSPL;

    f32x4 acc[4][NT] = {};

    for (int k0 = kbeg; k0 < kend; k0 += 64) {
        __syncthreads();
#pragma unroll
        for (int c = wave; c < 16; c += 4)
            gl_lds16(&A[(size_t)(m0 + c * 8 + lrow) * K + k0 + sblk * 8], &As[c * 512]);
#pragma unroll
        for (int c = wave; c < BN / 8; c += 4)
            gl_lds16(&Wt[(size_t)(n0 + c * 8 + lrow) * K + k0 + sblk * 8], &Bs[c * 512]);
        __syncthreads();
#pragma unroll
        for (int kk8 = 0; kk8 < 8; kk8 += 4) {
            bf16x8 af[4], bfr[NT];
#pragma unroll
            for (int t = 0; t < 4; ++t) {
                int R = wm + t * 16 + col16;
                af[t] = ldfrag(&As[R * 64 + (((kk8 + quad) ^ (R & 7)) << 3)]);
            }
#pragma unroll
            for (int t = 0; t < NT; ++t) {
                int R = wn + t * 16 + col16;
                bfr[t] = ldfrag(&Bs[R * 64 + (((kk8 + quad) ^ (R & 7)) << 3)]);
            }
#pragma unroll
            for (int mt = 0; mt < 4; ++mt)
#pragma unroll
                for (int nt = 0; nt < NT; ++nt)
                    acc[mt][nt] = MFMA16(af[mt], bfr[nt], acc[mt][nt]);
        }
    }

    float* outf = (float*)outp + ((KSPL > 1) ? (size_t)blockIdx.z * M * N : 0);
#pragma unroll
    for (int mt = 0; mt < 4; ++mt)
#pragma unroll
        for (int nt = 0; nt < NT; ++nt) {
            int col = n0 + wn + nt * 16 + col16;
            float bv = (KSPL == 1 || blockIdx.z == 0) ? bias[col] : 0.f;
            if (OMODE == 2 && col >= 2048) {
                // V tile: write transposed into vt[bh][d][s], packed over 4 consecutive s
                int dl = (col - 2048) & 63, hh = (col - 2048) >> 6;
                int row0 = m0 + wm + mt * 16 + quad * 4;
                int bb = row0 >> 11, sb = row0 & 2047;
                ushort4 w4;
                w4.x = f2bf(acc[mt][nt][0] + bv);
                w4.y = f2bf(acc[mt][nt][1] + bv);
                w4.z = f2bf(acc[mt][nt][2] + bv);
                w4.w = f2bf(acc[mt][nt][3] + bv);
                *(ushort4*)&vtp[(size_t)(bb * NH + hh) * DKH * SQL + (size_t)dl * SQL + sb] = w4;
            } else {
#pragma unroll
                for (int r = 0; r < 4; ++r) {
                    int row = m0 + wm + mt * 16 + quad * 4 + r;
                    float v = acc[mt][nt][r] + bv;
                    if (RELU) v = fmaxf(v, 0.f);
                    if (OMODE == 0)
                        outf[(size_t)row * N + col] = v;
                    else
                        ((unsigned short*)outp)[(size_t)row * N + col] = f2bf(v);
                }
            }
        }
}

// ---------------- flash attention: 8-wave blocks, 128 q-rows, direct bf16 out ----------------
// grid (16, 32), block 512. XCD swizzle: xcd owns bh in [4*xcd, 4*xcd+4) -> K/V L2-resident.
// Double-buffered K/V/lws staging, ONE barrier per tile; Ps per-wave (same-wave DS order);
// s_setprio(1) around MFMA clusters; softmax in exp2 domain (QSCALE folds log2e).
__global__ __launch_bounds__(512) void flash_kernel(const unsigned short* __restrict__ qkv,
                                                    const unsigned short* __restrict__ vt,
                                                    const float* __restrict__ logw,
                                                    unsigned short* __restrict__ attn_bf) {
    __shared__ unsigned short Ks[2][64 * 64];
    __shared__ unsigned short Vt[2][64 * 64];
    __shared__ unsigned short Ps[8][16][72];
    __shared__ float lws[2][64];

    const int tid = threadIdx.x, wave = tid >> 6, lane = tid & 63;
    const int col16 = lane & 15, quad = lane >> 4;
    const int lrow = lane >> 3, sblk = (lane & 7) ^ (lrow & 7);
    const int f = blockIdx.y * gridDim.x + blockIdx.x;
    const int g = f >> 3;
    const int bh = (f & 7) * 4 + (g & 3);
    const int q0 = (g >> 2) * 128;
    const int b = bh >> 4, h = bh & 15;

    const unsigned short* Kg = qkv + (size_t)b * SQL * QKVN + 1024 + h * DKH;
    const unsigned short* Vg = vt + (size_t)bh * DKH * SQL;

    bf16x8 qf[2];
    {
        const unsigned short* qrow =
            qkv + (size_t)(b * SQL + q0 + wave * 16 + col16) * QKVN + h * DKH;
        qf[0] = ldfrag(qrow + quad * 8);
        qf[1] = ldfrag(qrow + 32 + quad * 8);
    }
    bf16x8 ones;
    {
        short8 o8 = {0x3f80, 0x3f80, 0x3f80, 0x3f80, 0x3f80, 0x3f80, 0x3f80, 0x3f80};
        ones = __builtin_bit_cast(bf16x8, o8);
    }

    f32x4 o[4] = {};
    f32x4 lacc = {};

    {
        const int c = wave;
        gl_lds16(&Kg[(size_t)(c * 8 + lrow) * QKVN + sblk * 8], &Ks[0][c * 512]);
        gl_lds16(&Vg[(size_t)(c * 8 + lrow) * SQL + sblk * 8], &Vt[0][c * 512]);
        if (tid < 64) lws[0][tid] = logw[b * SQL + tid];
    }

    int cur = 0;
    for (int kt = 0; kt < SQL; kt += 64) {
        __syncthreads();
        if (kt + 64 < SQL) {
            const int c = wave;
            gl_lds16(&Kg[(size_t)(kt + 64 + c * 8 + lrow) * QKVN + sblk * 8],
                     &Ks[cur ^ 1][c * 512]);
            gl_lds16(&Vg[(size_t)(c * 8 + lrow) * SQL + kt + 64 + sblk * 8],
                     &Vt[cur ^ 1][c * 512]);
            if (tid < 64) lws[cur ^ 1][tid] = logw[b * SQL + kt + 64 + tid];
        }

        float pv[4][4];
        __builtin_amdgcn_s_setprio(1);
#pragma unroll
        for (int nt = 0; nt < 4; ++nt) {
            int R = nt * 16 + col16;
            f32x4 s4 = {};
            s4 = MFMA16(qf[0], ldfrag(&Ks[cur][R * 64 + ((quad ^ (R & 7)) << 3)]), s4);
            s4 = MFMA16(qf[1], ldfrag(&Ks[cur][R * 64 + (((4 + quad) ^ (R & 7)) << 3)]), s4);
            float lw = lws[cur][R];
#pragma unroll
            for (int r = 0; r < 4; ++r)
                pv[nt][r] = __builtin_amdgcn_exp2f(s4[r] + lw);
        }
        __builtin_amdgcn_s_setprio(0);
#pragma unroll
        for (int nt = 0; nt < 4; ++nt)
#pragma unroll
            for (int r = 0; r < 4; ++r)
                *(__bf16*)&Ps[wave][quad * 4 + r][nt * 16 + col16] = (__bf16)pv[nt][r];

#pragma unroll
        for (int kk8 = 0; kk8 < 8; kk8 += 4) {
            bf16x8 psf = ldfrag(&Ps[wave][col16][(kk8 + quad) << 3]);
            __builtin_amdgcn_s_setprio(1);
            lacc = MFMA16(ones, psf, lacc);
#pragma unroll
            for (int dt = 0; dt < 4; ++dt) {
                int R = dt * 16 + col16;
                bf16x8 vf = ldfrag(&Vt[cur][R * 64 + (((kk8 + quad) ^ (R & 7)) << 3)]);
                o[dt] = MFMA16(vf, psf, o[dt]);
            }
            __builtin_amdgcn_s_setprio(0);
        }
        cur ^= 1;
    }

    const float rl = 1.0f / lacc[0];
    const int qrow = b * SQL + q0 + wave * 16 + col16;
#pragma unroll
    for (int dt = 0; dt < 4; ++dt) {
        ushort4 h4;
        h4.x = f2bf(o[dt][0] * rl);
        h4.y = f2bf(o[dt][1] * rl);
        h4.z = f2bf(o[dt][2] * rl);
        h4.w = f2bf(o[dt][3] * rl);
        *(ushort4*)&attn_bf[(size_t)qrow * DM + h * DKH + dt * 16 + quad * 4] = h4;
    }
}

// ---------------- LN1: h = LN(x + d0 + d1); out fp32 + bf16 ----------------
__global__ __launch_bounds__(256) void ln1_kernel(const float* __restrict__ x,
                                                  const float* __restrict__ d0,
                                                  const float* __restrict__ d1,
                                                  const float* __restrict__ g,
                                                  const float* __restrict__ be,
                                                  float* __restrict__ hf,
                                                  unsigned short* __restrict__ hb) {
    const int row = blockIdx.x, tid = threadIdx.x;
    float4 xv = *(const float4*)&x[(size_t)row * DM + tid * 4];
    float4 av = *(const float4*)&d0[(size_t)row * DM + tid * 4];
    float4 bv = *(const float4*)&d1[(size_t)row * DM + tid * 4];
    float v[4] = {xv.x + av.x + bv.x, xv.y + av.y + bv.y, xv.z + av.z + bv.z,
                  xv.w + av.w + bv.w};
    float s = v[0] + v[1] + v[2] + v[3];
    float ss = v[0] * v[0] + v[1] * v[1] + v[2] * v[2] + v[3] * v[3];
#pragma unroll
    for (int m = 1; m < 64; m <<= 1) { s += __shfl_xor(s, m); ss += __shfl_xor(ss, m); }
    __shared__ float sb[4], ssb[4];
    if ((tid & 63) == 0) { sb[tid >> 6] = s; ssb[tid >> 6] = ss; }
    __syncthreads();
    s = sb[0] + sb[1] + sb[2] + sb[3];
    ss = ssb[0] + ssb[1] + ssb[2] + ssb[3];
    float mu = s * (1.f / DM);
    float var = fmaxf(ss * (1.f / DM) - mu * mu, 0.f);
    float rs = rsqrtf(var + 1e-3f);
#pragma unroll
    for (int i = 0; i < 4; ++i) {
        int c = tid * 4 + i;
        float y = (v[i] - mu) * rs * g[c] + be[c];
        hf[(size_t)row * DM + c] = y;
        hb[(size_t)row * DM + c] = f2bf(y);
    }
}

// ---------------- LN2: out = LN(h + d0 + d1) fp32 ----------------
__global__ __launch_bounds__(256) void ln2_kernel(const float* __restrict__ hf,
                                                  const float* __restrict__ d0,
                                                  const float* __restrict__ d1,
                                                  const float* __restrict__ g,
                                                  const float* __restrict__ be,
                                                  float* __restrict__ outp) {
    const int row = blockIdx.x, tid = threadIdx.x;
    float4 hv = *(const float4*)&hf[(size_t)row * DM + tid * 4];
    float4 av = *(const float4*)&d0[(size_t)row * DM + tid * 4];
    float4 bv = *(const float4*)&d1[(size_t)row * DM + tid * 4];
    float v[4] = {hv.x + av.x + bv.x, hv.y + av.y + bv.y, hv.z + av.z + bv.z,
                  hv.w + av.w + bv.w};
    float s = v[0] + v[1] + v[2] + v[3];
    float ss = v[0] * v[0] + v[1] * v[1] + v[2] * v[2] + v[3] * v[3];
#pragma unroll
    for (int m = 1; m < 64; m <<= 1) { s += __shfl_xor(s, m); ss += __shfl_xor(ss, m); }
    __shared__ float sb[4], ssb[4];
    if ((tid & 63) == 0) { sb[tid >> 6] = s; ssb[tid >> 6] = ss; }
    __syncthreads();
    s = sb[0] + sb[1] + sb[2] + sb[3];
    ss = ssb[0] + ssb[1] + ssb[2] + ssb[3];
    float mu = s * (1.f / DM);
    float var = fmaxf(ss * (1.f / DM) - mu * mu, 0.f);
    float rs = rsqrtf(var + 1e-3f);
    float4 ov;
    ov.x = (v[0] - mu) * rs * g[tid * 4 + 0] + be[tid * 4 + 0];
    ov.y = (v[1] - mu) * rs * g[tid * 4 + 1] + be[tid * 4 + 1];
    ov.z = (v[2] - mu) * rs * g[tid * 4 + 2] + be[tid * 4 + 2];
    ov.w = (v[3] - mu) * rs * g[tid * 4 + 3] + be[tid * 4 + 3];
    *(float4*)&outp[(size_t)row * DM + tid * 4] = ov;
}

extern "C" void kernel_launch(void* const* d_in, const int* in_sizes, int n_in,
                              void* d_out, int out_size, void* d_ws, size_t ws_size,
                              hipStream_t stream) {
    const float* x   = (const float*)d_in[0];
    const float* wts = (const float*)d_in[1];
    const float* Wq  = (const float*)d_in[2];
    const float* bq  = (const float*)d_in[3];
    const float* Wk  = (const float*)d_in[4];
    const float* bk  = (const float*)d_in[5];
    const float* Wv  = (const float*)d_in[6];
    const float* bv  = (const float*)d_in[7];
    const float* Wo  = (const float*)d_in[8];
    const float* bo  = (const float*)d_in[9];
    const float* W1  = (const float*)d_in[10];
    const float* b1  = (const float*)d_in[11];
    const float* W2  = (const float*)d_in[12];
    const float* b2  = (const float*)d_in[13];
    const float* g1  = (const float*)d_in[14];
    const float* be1 = (const float*)d_in[15];
    const float* g2  = (const float*)d_in[16];
    const float* be2 = (const float*)d_in[17];

    char* ws = (char*)d_ws;
    const size_t MB = 1u << 20;
    unsigned short* qkv_bf  = (unsigned short*)(ws + 0 * MB);
    unsigned short* vt      = (unsigned short*)(ws + 24 * MB);
    unsigned short* x_bf    = (unsigned short*)(ws + 32 * MB);
    unsigned short* wqkv_t  = (unsigned short*)(ws + 40 * MB);
    unsigned short* Wo_t    = (unsigned short*)(ws + 46 * MB);
    unsigned short* W1_t    = (unsigned short*)(ws + 48 * MB);
    float* h_f32            = (float*)(ws + 64 * MB);
    unsigned short* h_bf    = (unsigned short*)(ws + 80 * MB);
    unsigned short* W2_t    = (unsigned short*)(ws + 88 * MB);
    float* bqkv             = (float*)(ws + 96 * MB);
    float* logw             = (float*)(ws + 96 * MB + 0x8000);
    unsigned short* attn_bf = (unsigned short*)(ws + 32 * MB);
    float* attnproj         = (float*)(ws + 0 * MB);   // partials [0,16),[16,32)
    unsigned short* ffn1_bf = (unsigned short*)(ws + 0 * MB);
    float* ffn2             = (float*)(ws + 32 * MB);  // partials [32,48),[48,64)

    // 1. prep (single launch)
    prep_all<<<16412, 256, 0, stream>>>(Wq, Wk, Wv, Wo, W1, W2, x, wts, bq, bk, bv,
                                        wqkv_t, Wo_t, W1_t, W2_t, x_bf, logw, bqkv);

    // 2. fused QKV projection; V written directly transposed into vt (R2 config)
    gemm_kernel<128, false, 2, 1><<<dim3(QKVN / 128, MROWS / 128), 256, 0, stream>>>(
        x_bf, wqkv_t, bqkv, qkv_bf, vt, MROWS, QKVN, DM);

    // 3. attention
    flash_kernel<<<dim3(SQL / 128, NB * NH), 512, 0, stream>>>(qkv_bf, vt, logw, attn_bf);

    // 4. O projection (BN=128, split-K 2: halves A re-reads vs BN=64) + LN1
    gemm_kernel<128, false, 0, 2><<<dim3(DM / 128, MROWS / 128, 2), 256, 0, stream>>>(
        attn_bf, Wo_t, bo, attnproj, nullptr, MROWS, DM, DM);
    ln1_kernel<<<MROWS, 256, 0, stream>>>(x, attnproj, attnproj + (size_t)MROWS * DM,
                                          g1, be1, h_f32, h_bf);

    // 5. FFN1 (R2 config); FFN2 (BN=128 split-K 2: A re-reads 16->8) + LN2
    gemm_kernel<128, true, 1, 1><<<dim3(DFF / 128, MROWS / 128), 256, 0, stream>>>(
        h_bf, W1_t, b1, ffn1_bf, nullptr, MROWS, DFF, DM);
    gemm_kernel<128, false, 0, 2><<<dim3(DM / 128, MROWS / 128, 2), 256, 0, stream>>>(
        ffn1_bf, W2_t, b2, ffn2, nullptr, MROWS, DM, DFF);
    ln2_kernel<<<MROWS, 256, 0, stream>>>(h_f32, ffn2, ffn2 + (size_t)MROWS * DM,
                                          g2, be2, (float*)d_out);
}

// Round 6
// 341.645 us; speedup vs baseline: 1.0526x; 1.0526x over previous
//
#include <hip/hip_runtime.h>
#include <cstdint>
#include <cstddef>

#define DM 1024
#define NH 16
#define DKH 64
#define DFF 4096
#define NB 2
#define SQL 2048
#define MROWS (NB * SQL) /* 4096 */
#define QKVN 3072

typedef __attribute__((ext_vector_type(8))) __bf16 bf16x8;
typedef __attribute__((ext_vector_type(8))) short short8;
typedef __attribute__((ext_vector_type(4))) float f32x4;

__device__ __forceinline__ unsigned short f2bf(float f) {
    unsigned u = __float_as_uint(f);
    u += 0x7fffu + ((u >> 16) & 1u);
    return (unsigned short)(u >> 16);
}
__device__ __forceinline__ bf16x8 ldfrag(const unsigned short* p) {
    return __builtin_bit_cast(bf16x8, *(const short8*)p);
}
__device__ __forceinline__ void gl_lds16(const void* g, void* lds) {
    __builtin_amdgcn_global_load_lds(
        (const __attribute__((address_space(1))) unsigned int*)g,
        (__attribute__((address_space(3))) unsigned int*)lds, 16, 0, 0);
}
#define MFMA16(a, b, c) __builtin_amdgcn_mfma_f32_16x16x32_bf16(a, b, c, 0, 0, 0)

// Q-side scale: 1/sqrt(64) * log2(e), so softmax runs in exp2 domain (raw v_exp_f32).
#define QSCALE 0.18033688011112042f

// ---------------- merged prep: weight transposes + x cast + logw + bqkv ----------------
__global__ __launch_bounds__(256) void prep_all(const float* __restrict__ Wq,
                                                const float* __restrict__ Wk,
                                                const float* __restrict__ Wv,
                                                const float* __restrict__ Wo,
                                                const float* __restrict__ W1,
                                                const float* __restrict__ W2,
                                                const float* __restrict__ x,
                                                const float* __restrict__ wts,
                                                const float* __restrict__ bq,
                                                const float* __restrict__ bk,
                                                const float* __restrict__ bv,
                                                unsigned short* __restrict__ wqkv_t,
                                                unsigned short* __restrict__ Wo_t,
                                                unsigned short* __restrict__ W1_t,
                                                unsigned short* __restrict__ W2_t,
                                                unsigned short* __restrict__ x_bf,
                                                float* __restrict__ logw,
                                                float* __restrict__ bqkv) {
    const int t = blockIdx.x, tid = threadIdx.x;
    if (t >= 12288) {
        if (t < 16384) {
            int i = ((t - 12288) * 256 + tid) * 4;
            float4 v = *(const float4*)&x[i];
            ushort4 o;
            o.x = f2bf(v.x); o.y = f2bf(v.y); o.z = f2bf(v.z); o.w = f2bf(v.w);
            *(ushort4*)&x_bf[i] = o;
        } else if (t < 16400) {
            int i = (t - 16384) * 256 + tid;
            logw[i] = log2f(wts[i] + 1e-20f);  // log2 domain for exp2 softmax
        } else {
            int i = (t - 16400) * 256 + tid;
            if (i < QKVN)
                bqkv[i] = i < 1024 ? bq[i] * QSCALE : (i < 2048 ? bk[i - 1024] : bv[i - 2048]);
        }
        return;
    }
    __shared__ float tile[32][33];
    const float* in;
    unsigned short* out;
    int K = DM, N = DM, n0, k0;
    float scale = 1.f;
    if (t < 1024)      { in = Wq; out = wqkv_t;                      scale = QSCALE;
                         n0 = (t & 31) * 32;          k0 = (t >> 5) * 32; }
    else if (t < 2048) { in = Wk; out = wqkv_t + (size_t)1024 * DM;
                         n0 = ((t - 1024) & 31) * 32; k0 = ((t - 1024) >> 5) * 32; }
    else if (t < 3072) { in = Wv; out = wqkv_t + (size_t)2048 * DM;
                         n0 = ((t - 2048) & 31) * 32; k0 = ((t - 2048) >> 5) * 32; }
    else if (t < 4096) { in = Wo; out = Wo_t;
                         n0 = ((t - 3072) & 31) * 32; k0 = ((t - 3072) >> 5) * 32; }
    else if (t < 8192) { in = W1; out = W1_t; N = DFF;
                         n0 = ((t - 4096) & 127) * 32; k0 = ((t - 4096) >> 7) * 32; }
    else               { in = W2; out = W2_t; K = DFF;
                         n0 = ((t - 8192) & 31) * 32;  k0 = ((t - 8192) >> 5) * 32; }
    const int tx = threadIdx.x & 31, ty = threadIdx.x >> 5;
#pragma unroll
    for (int i = 0; i < 32; i += 8)
        tile[ty + i][tx] = in[(size_t)(k0 + ty + i) * N + n0 + tx];
    __syncthreads();
#pragma unroll
    for (int i = 0; i < 32; i += 8)
        out[(size_t)(n0 + ty + i) * K + k0 + tx] = f2bf(tile[tx][ty + i] * scale);
}

// ---------------- bf16 GEMM: C[M,N] = A[M,K] @ Wt[N,K]^T + bias ----------------
// 128 x BN tile, BK=64, global_load_lds 16B staging, XOR-swizzled 16B blocks.
// XCD swizzle: xcd = flat%8 owns gridDim.x/8 consecutive n-blocks (B L2-resident).
// OMODE: 0 = fp32 partials (out + z*M*N), 1 = bf16 row-major, 2 = bf16 row-major for
//        col<2048 and V-transposed (vt[bh][d][s]) for col>=2048 (QKV fused epilogue).
template <int BN, bool RELU, int OMODE, int KSPL>
__global__ __launch_bounds__(256) void gemm_kernel(const unsigned short* __restrict__ A,
                                                   const unsigned short* __restrict__ Wt,
                                                   const float* __restrict__ bias,
                                                   void* __restrict__ outp,
                                                   unsigned short* __restrict__ vtp,
                                                   int M, int N, int K) {
    constexpr int NT = BN / 32;
    __shared__ unsigned short As[128 * 64];
    __shared__ unsigned short Bs[BN * 64];
    const int tid = threadIdx.x;
    const int wave = tid >> 6, lane = tid & 63;
    const int col16 = lane & 15, quad = lane >> 4;
    const int lrow = lane >> 3, sblk = (lane & 7) ^ (lrow & 7);
    const int f = blockIdx.y * gridDim.x + blockIdx.x;
    const int nper = gridDim.x >> 3;
    const int bx = (f & 7) * nper + (f >> 3) % nper;
    const int by = (f >> 3) / nper;
    const int m0 = by * 128, n0 = bx * BN;
    const int wm = (wave >> 1) * 64, wn = (wave & 1) * (BN / 2);
    const int kbeg = (KSPL > 1) ? blockIdx.z * (K / KSPL) : 0;
    const int kend = kbeg + K / KSPL;

    f32x4 acc[4][NT] = {};

    for (int k0 = kbeg; k0 < kend; k0 += 64) {
        __syncthreads();
#pragma unroll
        for (int c = wave; c < 16; c += 4)
            gl_lds16(&A[(size_t)(m0 + c * 8 + lrow) * K + k0 + sblk * 8], &As[c * 512]);
#pragma unroll
        for (int c = wave; c < BN / 8; c += 4)
            gl_lds16(&Wt[(size_t)(n0 + c * 8 + lrow) * K + k0 + sblk * 8], &Bs[c * 512]);
        __syncthreads();
#pragma unroll
        for (int kk8 = 0; kk8 < 8; kk8 += 4) {
            bf16x8 af[4], bfr[NT];
#pragma unroll
            for (int t = 0; t < 4; ++t) {
                int R = wm + t * 16 + col16;
                af[t] = ldfrag(&As[R * 64 + (((kk8 + quad) ^ (R & 7)) << 3)]);
            }
#pragma unroll
            for (int t = 0; t < NT; ++t) {
                int R = wn + t * 16 + col16;
                bfr[t] = ldfrag(&Bs[R * 64 + (((kk8 + quad) ^ (R & 7)) << 3)]);
            }
#pragma unroll
            for (int mt = 0; mt < 4; ++mt)
#pragma unroll
                for (int nt = 0; nt < NT; ++nt)
                    acc[mt][nt] = MFMA16(af[mt], bfr[nt], acc[mt][nt]);
        }
    }

    float* outf = (float*)outp + ((KSPL > 1) ? (size_t)blockIdx.z * M * N : 0);
#pragma unroll
    for (int mt = 0; mt < 4; ++mt)
#pragma unroll
        for (int nt = 0; nt < NT; ++nt) {
            int col = n0 + wn + nt * 16 + col16;
            float bv = (KSPL == 1 || blockIdx.z == 0) ? bias[col] : 0.f;
            if (OMODE == 2 && col >= 2048) {
                int dl = (col - 2048) & 63, hh = (col - 2048) >> 6;
                int row0 = m0 + wm + mt * 16 + quad * 4;
                int bb = row0 >> 11, sb = row0 & 2047;
                ushort4 w4;
                w4.x = f2bf(acc[mt][nt][0] + bv);
                w4.y = f2bf(acc[mt][nt][1] + bv);
                w4.z = f2bf(acc[mt][nt][2] + bv);
                w4.w = f2bf(acc[mt][nt][3] + bv);
                *(ushort4*)&vtp[(size_t)(bb * NH + hh) * DKH * SQL + (size_t)dl * SQL + sb] = w4;
            } else {
#pragma unroll
                for (int r = 0; r < 4; ++r) {
                    int row = m0 + wm + mt * 16 + quad * 4 + r;
                    float v = acc[mt][nt][r] + bv;
                    if (RELU) v = fmaxf(v, 0.f);
                    if (OMODE == 0)
                        outf[(size_t)row * N + col] = v;
                    else
                        ((unsigned short*)outp)[(size_t)row * N + col] = f2bf(v);
                }
            }
        }
}

// ---------------- flash attention: 8-wave blocks, 128 q-rows, direct bf16 out ----------------
// grid (16, 32), block 512. XCD swizzle: xcd owns bh in [4*xcd, 4*xcd+4) -> K/V L2-resident.
// Double-buffered K/V staging, ONE barrier per tile; Ps per-wave (same-wave DS order);
// s_setprio(1) around MFMA clusters; softmax in exp2 domain (QSCALE folds log2e).
// R6: logw read per-lane straight to registers (L1/L2-resident, 16 KB) -- removes the
// divergent tid<64 staging, the lws LDS array, and its reads from the drain set.
__global__ __launch_bounds__(512) void flash_kernel(const unsigned short* __restrict__ qkv,
                                                    const unsigned short* __restrict__ vt,
                                                    const float* __restrict__ logw,
                                                    unsigned short* __restrict__ attn_bf) {
    __shared__ unsigned short Ks[2][64 * 64];
    __shared__ unsigned short Vt[2][64 * 64];
    __shared__ unsigned short Ps[8][16][72];

    const int tid = threadIdx.x, wave = tid >> 6, lane = tid & 63;
    const int col16 = lane & 15, quad = lane >> 4;
    const int lrow = lane >> 3, sblk = (lane & 7) ^ (lrow & 7);
    const int f = blockIdx.y * gridDim.x + blockIdx.x;
    const int g = f >> 3;
    const int bh = (f & 7) * 4 + (g & 3);
    const int q0 = (g >> 2) * 128;
    const int b = bh >> 4, h = bh & 15;

    const unsigned short* Kg = qkv + (size_t)b * SQL * QKVN + 1024 + h * DKH;
    const unsigned short* Vg = vt + (size_t)bh * DKH * SQL;
    const float* lwg = logw + b * SQL + col16;

    bf16x8 qf[2];
    {
        const unsigned short* qrow =
            qkv + (size_t)(b * SQL + q0 + wave * 16 + col16) * QKVN + h * DKH;
        qf[0] = ldfrag(qrow + quad * 8);
        qf[1] = ldfrag(qrow + 32 + quad * 8);
    }
    bf16x8 ones;
    {
        short8 o8 = {0x3f80, 0x3f80, 0x3f80, 0x3f80, 0x3f80, 0x3f80, 0x3f80, 0x3f80};
        ones = __builtin_bit_cast(bf16x8, o8);
    }

    f32x4 o[4] = {};
    f32x4 lacc = {};

    {
        const int c = wave;
        gl_lds16(&Kg[(size_t)(c * 8 + lrow) * QKVN + sblk * 8], &Ks[0][c * 512]);
        gl_lds16(&Vg[(size_t)(c * 8 + lrow) * SQL + sblk * 8], &Vt[0][c * 512]);
    }

    int cur = 0;
    for (int kt = 0; kt < SQL; kt += 64) {
        __syncthreads();
        // per-lane logw for this tile: 4 scalar loads, L1/L2-hit, consumed after QK MFMAs
        float lwr[4];
#pragma unroll
        for (int nt = 0; nt < 4; ++nt) lwr[nt] = lwg[kt + nt * 16];
        if (kt + 64 < SQL) {
            const int c = wave;
            gl_lds16(&Kg[(size_t)(kt + 64 + c * 8 + lrow) * QKVN + sblk * 8],
                     &Ks[cur ^ 1][c * 512]);
            gl_lds16(&Vg[(size_t)(c * 8 + lrow) * SQL + kt + 64 + sblk * 8],
                     &Vt[cur ^ 1][c * 512]);
        }

        float pv[4][4];
        __builtin_amdgcn_s_setprio(1);
#pragma unroll
        for (int nt = 0; nt < 4; ++nt) {
            int R = nt * 16 + col16;
            f32x4 s4 = {};
            s4 = MFMA16(qf[0], ldfrag(&Ks[cur][R * 64 + ((quad ^ (R & 7)) << 3)]), s4);
            s4 = MFMA16(qf[1], ldfrag(&Ks[cur][R * 64 + (((4 + quad) ^ (R & 7)) << 3)]), s4);
            float lw = lwr[nt];
#pragma unroll
            for (int r = 0; r < 4; ++r)
                pv[nt][r] = __builtin_amdgcn_exp2f(s4[r] + lw);
        }
        __builtin_amdgcn_s_setprio(0);
#pragma unroll
        for (int nt = 0; nt < 4; ++nt)
#pragma unroll
            for (int r = 0; r < 4; ++r)
                *(__bf16*)&Ps[wave][quad * 4 + r][nt * 16 + col16] = (__bf16)pv[nt][r];

#pragma unroll
        for (int kk8 = 0; kk8 < 8; kk8 += 4) {
            bf16x8 psf = ldfrag(&Ps[wave][col16][(kk8 + quad) << 3]);
            __builtin_amdgcn_s_setprio(1);
            lacc = MFMA16(ones, psf, lacc);
#pragma unroll
            for (int dt = 0; dt < 4; ++dt) {
                int R = dt * 16 + col16;
                bf16x8 vf = ldfrag(&Vt[cur][R * 64 + (((kk8 + quad) ^ (R & 7)) << 3)]);
                o[dt] = MFMA16(vf, psf, o[dt]);
            }
            __builtin_amdgcn_s_setprio(0);
        }
        cur ^= 1;
    }

    const float rl = 1.0f / lacc[0];
    const int qrow = b * SQL + q0 + wave * 16 + col16;
#pragma unroll
    for (int dt = 0; dt < 4; ++dt) {
        ushort4 h4;
        h4.x = f2bf(o[dt][0] * rl);
        h4.y = f2bf(o[dt][1] * rl);
        h4.z = f2bf(o[dt][2] * rl);
        h4.w = f2bf(o[dt][3] * rl);
        *(ushort4*)&attn_bf[(size_t)qrow * DM + h * DKH + dt * 16 + quad * 4] = h4;
    }
}

// ---------------- LN1: h = LN(x + d0 + d1); out fp32 + bf16 ----------------
__global__ __launch_bounds__(256) void ln1_kernel(const float* __restrict__ x,
                                                  const float* __restrict__ d0,
                                                  const float* __restrict__ d1,
                                                  const float* __restrict__ g,
                                                  const float* __restrict__ be,
                                                  float* __restrict__ hf,
                                                  unsigned short* __restrict__ hb) {
    const int row = blockIdx.x, tid = threadIdx.x;
    float4 xv = *(const float4*)&x[(size_t)row * DM + tid * 4];
    float4 av = *(const float4*)&d0[(size_t)row * DM + tid * 4];
    float4 bv = *(const float4*)&d1[(size_t)row * DM + tid * 4];
    float v[4] = {xv.x + av.x + bv.x, xv.y + av.y + bv.y, xv.z + av.z + bv.z,
                  xv.w + av.w + bv.w};
    float s = v[0] + v[1] + v[2] + v[3];
    float ss = v[0] * v[0] + v[1] * v[1] + v[2] * v[2] + v[3] * v[3];
#pragma unroll
    for (int m = 1; m < 64; m <<= 1) { s += __shfl_xor(s, m); ss += __shfl_xor(ss, m); }
    __shared__ float sb[4], ssb[4];
    if ((tid & 63) == 0) { sb[tid >> 6] = s; ssb[tid >> 6] = ss; }
    __syncthreads();
    s = sb[0] + sb[1] + sb[2] + sb[3];
    ss = ssb[0] + ssb[1] + ssb[2] + ssb[3];
    float mu = s * (1.f / DM);
    float var = fmaxf(ss * (1.f / DM) - mu * mu, 0.f);
    float rs = rsqrtf(var + 1e-3f);
#pragma unroll
    for (int i = 0; i < 4; ++i) {
        int c = tid * 4 + i;
        float y = (v[i] - mu) * rs * g[c] + be[c];
        hf[(size_t)row * DM + c] = y;
        hb[(size_t)row * DM + c] = f2bf(y);
    }
}

// ---------------- LN2: out = LN(h + d0 + d1) fp32 ----------------
__global__ __launch_bounds__(256) void ln2_kernel(const float* __restrict__ hf,
                                                  const float* __restrict__ d0,
                                                  const float* __restrict__ d1,
                                                  const float* __restrict__ g,
                                                  const float* __restrict__ be,
                                                  float* __restrict__ outp) {
    const int row = blockIdx.x, tid = threadIdx.x;
    float4 hv = *(const float4*)&hf[(size_t)row * DM + tid * 4];
    float4 av = *(const float4*)&d0[(size_t)row * DM + tid * 4];
    float4 bv = *(const float4*)&d1[(size_t)row * DM + tid * 4];
    float v[4] = {hv.x + av.x + bv.x, hv.y + av.y + bv.y, hv.z + av.z + bv.z,
                  hv.w + av.w + bv.w};
    float s = v[0] + v[1] + v[2] + v[3];
    float ss = v[0] * v[0] + v[1] * v[1] + v[2] * v[2] + v[3] * v[3];
#pragma unroll
    for (int m = 1; m < 64; m <<= 1) { s += __shfl_xor(s, m); ss += __shfl_xor(ss, m); }
    __shared__ float sb[4], ssb[4];
    if ((tid & 63) == 0) { sb[tid >> 6] = s; ssb[tid >> 6] = ss; }
    __syncthreads();
    s = sb[0] + sb[1] + sb[2] + sb[3];
    ss = ssb[0] + ssb[1] + ssb[2] + ssb[3];
    float mu = s * (1.f / DM);
    float var = fmaxf(ss * (1.f / DM) - mu * mu, 0.f);
    float rs = rsqrtf(var + 1e-3f);
    float4 ov;
    ov.x = (v[0] - mu) * rs * g[tid * 4 + 0] + be[tid * 4 + 0];
    ov.y = (v[1] - mu) * rs * g[tid * 4 + 1] + be[tid * 4 + 1];
    ov.z = (v[2] - mu) * rs * g[tid * 4 + 2] + be[tid * 4 + 2];
    ov.w = (v[3] - mu) * rs * g[tid * 4 + 3] + be[tid * 4 + 3];
    *(float4*)&outp[(size_t)row * DM + tid * 4] = ov;
}

extern "C" void kernel_launch(void* const* d_in, const int* in_sizes, int n_in,
                              void* d_out, int out_size, void* d_ws, size_t ws_size,
                              hipStream_t stream) {
    const float* x   = (const float*)d_in[0];
    const float* wts = (const float*)d_in[1];
    const float* Wq  = (const float*)d_in[2];
    const float* bq  = (const float*)d_in[3];
    const float* Wk  = (const float*)d_in[4];
    const float* bk  = (const float*)d_in[5];
    const float* Wv  = (const float*)d_in[6];
    const float* bv  = (const float*)d_in[7];
    const float* Wo  = (const float*)d_in[8];
    const float* bo  = (const float*)d_in[9];
    const float* W1  = (const float*)d_in[10];
    const float* b1  = (const float*)d_in[11];
    const float* W2  = (const float*)d_in[12];
    const float* b2  = (const float*)d_in[13];
    const float* g1  = (const float*)d_in[14];
    const float* be1 = (const float*)d_in[15];
    const float* g2  = (const float*)d_in[16];
    const float* be2 = (const float*)d_in[17];

    char* ws = (char*)d_ws;
    const size_t MB = 1u << 20;
    unsigned short* qkv_bf  = (unsigned short*)(ws + 0 * MB);
    unsigned short* vt      = (unsigned short*)(ws + 24 * MB);
    unsigned short* x_bf    = (unsigned short*)(ws + 32 * MB);
    unsigned short* wqkv_t  = (unsigned short*)(ws + 40 * MB);
    unsigned short* Wo_t    = (unsigned short*)(ws + 46 * MB);
    unsigned short* W1_t    = (unsigned short*)(ws + 48 * MB);
    float* h_f32            = (float*)(ws + 64 * MB);
    unsigned short* h_bf    = (unsigned short*)(ws + 80 * MB);
    unsigned short* W2_t    = (unsigned short*)(ws + 88 * MB);
    float* bqkv             = (float*)(ws + 96 * MB);
    float* logw             = (float*)(ws + 96 * MB + 0x8000);
    unsigned short* attn_bf = (unsigned short*)(ws + 32 * MB);
    float* attnproj         = (float*)(ws + 0 * MB);   // partials [0,16),[16,32)
    unsigned short* ffn1_bf = (unsigned short*)(ws + 0 * MB);
    float* ffn2             = (float*)(ws + 32 * MB);  // partials [32,48),[48,64)

    // 1. prep (single launch)
    prep_all<<<16412, 256, 0, stream>>>(Wq, Wk, Wv, Wo, W1, W2, x, wts, bq, bk, bv,
                                        wqkv_t, Wo_t, W1_t, W2_t, x_bf, logw, bqkv);

    // 2. fused QKV projection; V written directly transposed into vt (R2 config)
    gemm_kernel<128, false, 2, 1><<<dim3(QKVN / 128, MROWS / 128), 256, 0, stream>>>(
        x_bf, wqkv_t, bqkv, qkv_bf, vt, MROWS, QKVN, DM);

    // 3. attention
    flash_kernel<<<dim3(SQL / 128, NB * NH), 512, 0, stream>>>(qkv_bf, vt, logw, attn_bf);

    // 4. O projection (BN=64, split-K 2 -- R2 config) + LN1
    gemm_kernel<64, false, 0, 2><<<dim3(DM / 64, MROWS / 128, 2), 256, 0, stream>>>(
        attn_bf, Wo_t, bo, attnproj, nullptr, MROWS, DM, DM);
    ln1_kernel<<<MROWS, 256, 0, stream>>>(x, attnproj, attnproj + (size_t)MROWS * DM,
                                          g1, be1, h_f32, h_bf);

    // 5. FFN1 (R2 config); FFN2 (BN=64 split-K 2 -- R2 config) + LN2
    gemm_kernel<128, true, 1, 1><<<dim3(DFF / 128, MROWS / 128), 256, 0, stream>>>(
        h_bf, W1_t, b1, ffn1_bf, nullptr, MROWS, DFF, DM);
    gemm_kernel<64, false, 0, 2><<<dim3(DM / 64, MROWS / 128, 2), 256, 0, stream>>>(
        ffn1_bf, W2_t, b2, ffn2, nullptr, MROWS, DM, DFF);
    ln2_kernel<<<MROWS, 256, 0, stream>>>(h_f32, ffn2, ffn2 + (size_t)MROWS * DM,
                                          g2, be2, (float*)d_out);
}